// Round 12
// baseline (22.256 us; speedup 1.0000x reference)
//
#include <hip/hip_runtime.h>

// HistByProfMultiChannel: x (16,128,56,56) f32, hist_edges (128,10) f32,
// out (16,128,11) f32.
//
// R12: trans-free hot path, sigmoid Newton seed FIXED.
//  - R11 failed (absmax 351) because the reciprocal seed 48/17-32/17*x is
//    only valid on [0.5,1]; our operand xx = 1+u is in [1,2], where that
//    seed goes negative and Newton diverges. Correct [1,2] seed:
//    y0 = 24/17 - 8/17*x (minimax, +-1/17), two Newtons -> rel ~1.2e-5.
//  - Everything else identical to R11:
//    * exp2 via magic-round + deg-4 poly + exponent scale (pure VALU,
//      i<=-127 -> exact 0). Rel err ~4e-5.
//    * Biased geometric chain (2^88), anchors bins 0,1,6; unbias at end.
//    * Gaussian vg clamped to [LC,HC] (LC: nearest-bin biased t <= -130,
//      keeps sentinel finite; HC: ratio r <= 2^126).
//    * Sigmoid uses UNclamped v; mirror select for s<0.

#define NE 10
#define NBINS 11
#define HW 3136
#define HW4 784
#define NCH 128
#define BIAS 88.0f

typedef float v2f __attribute__((ext_vector_type(2)));

__device__ __forceinline__ float rfl(float xv) {
    return __int_as_float(__builtin_amdgcn_readfirstlane(__float_as_int(xv)));
}

// 2^t for both lanes of a v2f, pure VALU. Valid for t in (-4194304, 127];
// t <= -127 -> exactly 0. Rel err <= ~4e-5.
__device__ __forceinline__ v2f exp2p(v2f t) {
    const float MAGF = 12582912.0f;            // 1.5 * 2^23
    v2f m = t + (v2f){MAGF, MAGF};
    int ix = __float_as_int(m.x) - 0x4B400000;
    int iy = __float_as_int(m.y) - 0x4B400000;
    v2f f = t - (m - (v2f){MAGF, MAGF});       // f in [-0.5, 0.5]
    v2f p = (v2f){0.00961813f, 0.00961813f};
    p = p * f + (v2f){0.05550411f, 0.05550411f};
    p = p * f + (v2f){0.24022651f, 0.24022651f};
    p = p * f + (v2f){0.69314718f, 0.69314718f};
    p = p * f + (v2f){1.0f, 1.0f};
    ix = (ix < -127) ? -127 : ix;
    iy = (iy < -127) ? -127 : iy;
    v2f s;
    s.x = __int_as_float((ix + 127) << 23);
    s.y = __int_as_float((iy + 127) << 23);
    return p * s;
}

struct UniCoef {
    float A, B0, C0, B1, C1, B6, C6, dB, dC, rho, rho2, LC, HC, sB, sC;
};

// Two pixels through the biased chain + sigmoid, zero trans ops.
__device__ __forceinline__ void chain2(v2f v, const UniCoef& u, v2f* acc2) {
    v2f vg = __builtin_elementwise_min(
                 __builtin_elementwise_max(v, (v2f){u.LC, u.LC}),
                 (v2f){u.HC, u.HC});
    v2f q  = vg * vg;
    v2f t0 = u.A * q + (u.B0 * vg + u.C0);
    v2f t1 = u.A * q + (u.B1 * vg + u.C1);
    v2f t6 = u.A * q + (u.B6 * vg + u.C6);
    v2f rr = exp2p(u.dB * vg + (v2f){u.dC, u.dC});
    acc2[0] += exp2p(t0);
    v2f g = exp2p(t1);
    acc2[1] += g;
    g *= rr; acc2[2] += g; rr *= u.rho;
    g *= rr; acc2[3] += g; rr *= u.rho;
    g *= rr; acc2[4] += g; rr *= u.rho;
    g *= rr; acc2[5] += g; rr *= u.rho2;   // rr: r4 -> r6
    v2f h = exp2p(t6);
    acc2[6] += h;
    h *= rr; acc2[7] += h; rr *= u.rho;
    h *= rr; acc2[8] += h; rr *= u.rho;
    h *= rr; acc2[9] += h;
    // sigmoid: s = sB*v + sC (UNclamped v); sigma = 1/(1+2^s)
    v2f s = u.sB * v + (v2f){u.sC, u.sC};
    v2f a; a.x = fabsf(s.x); a.y = fabsf(s.y);
    v2f tt = __builtin_elementwise_max(-a, (v2f){-200.0f, -200.0f});
    v2f uu = exp2p(tt);                    // 2^{-|s|} in (0, 1]
    v2f xx = uu + (v2f){1.0f, 1.0f};       // in [1, 2]
    // 1/xx on [1,2]: seed 24/17 - 8/17*x (R11 used the [0.5,1] seed -> bug)
    v2f y  = (v2f){-0.47058824f, -0.47058824f} * xx
           + (v2f){1.41176471f, 1.41176471f};
    y = y * ((v2f){2.0f, 2.0f} - xx * y);
    y = y * ((v2f){2.0f, 2.0f} - xx * y);  // rel ~1.2e-5
    v2f qq = uu * y;                       // u/(1+u)
    v2f sig;
    sig.x = (s.x > 0.0f) ? qq.x : 1.0f - qq.x;
    sig.y = (s.y > 0.0f) ? qq.y : 1.0f - qq.y;
    acc2[10] += sig;
}

__global__ __launch_bounds__(256)
void hist_kernel(const float* __restrict__ x,
                 const float* __restrict__ edges,
                 float* __restrict__ out) {
    const int bc  = blockIdx.x;          // bt*NCH + c
    const int c   = bc & (NCH - 1);
    const int tid = threadIdx.x;

    const float LOG2E = 1.4426950408889634f;

    float e[NE];
    #pragma unroll
    for (int j = 0; j < NE; ++j) e[j] = rfl(edges[c * NE + j]);

    const float4* xp = (const float4*)(x + (size_t)bc * HW);
    float4 p0 = xp[tid];
    float4 p1 = xp[tid + 256];
    float4 p2 = xp[tid + 512];
    float4 p3;
    if (tid < (HW4 - 768)) p3 = xp[768 + tid];
    else { p3.x = p3.y = p3.z = p3.w = -1e18f; }   // sentinel -> all profiles 0

    v2f acc2[NBINS];
    #pragma unroll
    for (int j = 0; j < NBINS; ++j) acc2[j] = (v2f){0.f, 0.f};

    const float D = e[1] - e[0];
    bool uniform = (D > 1e-6f);
    #pragma unroll
    for (int j = 1; j < NE - 1; ++j)
        uniform = uniform && (fabsf((e[j + 1] - e[j]) - D) <= 1e-4f * fabsf(D));

    const float sB = rfl(-20.0f * LOG2E);
    const float sC = rfl(20.0f * LOG2E * e[NE - 1]);

    if (uniform) {
        UniCoef u;
        const float sg  = -D * (1.0f / 3.0f) + 1e-6f;
        const float A   = rfl(-0.5f * LOG2E / (sg * sg));   // < 0 (log2 space)
        const float mu1 = e[0] + 0.5f * D;
        const float mu6 = e[0] + 5.5f * D;
        u.A  = A;
        u.B0 = rfl(-2.0f * A * e[0]); u.C0 = rfl(A * e[0] * e[0] + BIAS);
        u.B1 = rfl(-2.0f * A * mu1);  u.C1 = rfl(A * mu1 * mu1 + BIAS);
        u.B6 = rfl(-2.0f * A * mu6);  u.C6 = rfl(A * mu6 * mu6 + BIAS);
        u.dB = rfl(-2.0f * A * D);
        u.dC = rfl(A * D * (mu1 + mu1 + D));
        u.rho  = rfl(__builtin_amdgcn_exp2f(2.0f * A * D * D));   // < 1
        u.rho2 = rfl(u.rho * u.rho);
        u.HC = rfl((126.0f - u.dC) / u.dB);               // r stays finite
        // LC: nearest-bin biased exponent <= -130 => everything ~0 there;
        // also keeps A*vg^2 finite for the -1e18 sentinel.
        u.LC = rfl(e[0] - __builtin_amdgcn_sqrtf((BIAS + 130.0f) / (-A)));
        u.sB = sB; u.sC = sC;

        chain2((v2f){p0.x, p0.y}, u, acc2);
        chain2((v2f){p0.z, p0.w}, u, acc2);
        chain2((v2f){p1.x, p1.y}, u, acc2);
        chain2((v2f){p1.z, p1.w}, u, acc2);
        chain2((v2f){p2.x, p2.y}, u, acc2);
        chain2((v2f){p2.z, p2.w}, u, acc2);
        chain2((v2f){p3.x, p3.y}, u, acc2);
        chain2((v2f){p3.z, p3.w}, u, acc2);
    } else {
        // General path: direct per-bin quadratic exp2 (rare; hw trans ok).
        float As[NE], Bs[NE], Cs[NE];
        {
            float mu = e[0];
            float s2 = (e[0] - e[1]) * (1.0f / 3.0f) + 1e-6f;
            float kk = -0.5f * LOG2E / (s2 * s2);
            As[0] = rfl(kk); Bs[0] = rfl(-2.0f * kk * mu); Cs[0] = rfl(kk * mu * mu);
        }
        #pragma unroll
        for (int j = 1; j < NE; ++j) {
            float mu = (e[j - 1] + e[j]) * 0.5f;
            float s2 = (e[j - 1] - e[j]) * (1.0f / 3.0f) + 1e-6f;
            float kk = -0.5f * LOG2E / (s2 * s2);
            As[j] = rfl(kk); Bs[j] = rfl(-2.0f * kk * mu); Cs[j] = rfl(kk * mu * mu);
        }
        float vsg[16] = {p0.x,p0.y,p0.z,p0.w, p1.x,p1.y,p1.z,p1.w,
                         p2.x,p2.y,p2.z,p2.w, p3.x,p3.y,p3.z,p3.w};
        #pragma unroll
        for (int k = 0; k < 16; ++k) {
            float v = vsg[k], v2 = v * v;
            #pragma unroll
            for (int j = 0; j < NE; ++j) {
                float arg = fmaf(As[j], v2, fmaf(Bs[j], v, Cs[j]));
                acc2[j].x += __builtin_amdgcn_exp2f(arg);
            }
            float den = 1.0f + __builtin_amdgcn_exp2f(fmaf(sB, v, sC));
            acc2[10].x += __builtin_amdgcn_rcpf(den);
        }
    }

    float acc[NBINS];
    #pragma unroll
    for (int j = 0; j < NBINS; ++j) acc[j] = acc2[j].x + acc2[j].y;

    // Wave (64-lane) reduce each accumulator.
    #pragma unroll
    for (int j = 0; j < NBINS; ++j) {
        float a = acc[j];
        #pragma unroll
        for (int off = 32; off > 0; off >>= 1)
            a += __shfl_down(a, off, 64);
        acc[j] = a;
    }

    // Cross-wave reduce via LDS (4 waves x 11 bins).
    __shared__ float red[4][NBINS];
    const int wave = tid >> 6;
    const int lane = tid & 63;
    if (lane == 0) {
        #pragma unroll
        for (int j = 0; j < NBINS; ++j) red[wave][j] = acc[j];
    }
    __syncthreads();
    if (tid < NBINS) {
        float s = red[0][tid] + red[1][tid] + red[2][tid] + red[3][tid];
        const float unb = (uniform && tid < NE) ? 0x1p-88f : 1.0f;
        out[(size_t)bc * NBINS + tid] = s * unb;
    }
}

extern "C" void kernel_launch(void* const* d_in, const int* in_sizes, int n_in,
                              void* d_out, int out_size, void* d_ws, size_t ws_size,
                              hipStream_t stream) {
    const float* x     = (const float*)d_in[0];
    const float* edges = (const float*)d_in[1];
    float* out         = (float*)d_out;
    hist_kernel<<<dim3(16 * NCH), dim3(256), 0, stream>>>(x, edges, out);
}

// Round 13
// 17.522 us; speedup vs baseline: 1.2702x; 1.2702x over previous
//
#include <hip/hip_runtime.h>

// HistByProfMultiChannel: x (16,128,56,56) f32, hist_edges (128,10) f32,
// out (16,128,11) f32.
//
// R13: half-step-ratio chain (8 trans/pair, was 12) + Newton sigmoid rcp +
//      chunk fencing for load/compute overlap.
//  - Uniform edges: r05 = exp2((dB/2)v + cH) is the bin0->bin1 ratio AND
//    r_full = r05^2 * 2^{1.5AD^2}. So exp2 calls per pair: t0, r05, t6,
//    sigmoid = 8 (R10 had t0,t1,t6,r,sig + 2 rcp = 12 trans). Fit: trans
//    ~18cy issue-blocking => C 304 -> ~248 cy/pair.
//  - BIAS 110 (was 88): anchor-FTZ boundary at |v-mu_a| > 0.603 where the
//    worst chained-bin true value is 2.7e-5. Headroom: 16px*2^110*64*4 =
//    2^122 < 2^128. acc[0..9] unbiased by 2^-110 at the end (exact).
//  - Sigmoid: hw exp2 + Newton reciprocal on [1,2] (seed 24/17 - 8/17*x,
//    2 iters, rel ~1.2e-5) -- saves 2 v_rcp/pair for ~5 pk ops.
//  - sched_barrier(0) between chunks: forces progressive vmcnt(3/2/1/0)
//    so chunk0 computes while chunks 1-3 stream (F=7.6us looked fully
//    serialized: wall = F + T_c exactly, rounds R9/R10).

#define NE 10
#define NBINS 11
#define HW 3136
#define HW4 784
#define NCH 128
#define BIAS 110.0f

typedef float v2f __attribute__((ext_vector_type(2)));

__device__ __forceinline__ float rfl(float xv) {
    return __int_as_float(__builtin_amdgcn_readfirstlane(__float_as_int(xv)));
}
__device__ __forceinline__ v2f exp2v(v2f a) {
    v2f r;
    r.x = __builtin_amdgcn_exp2f(a.x);
    r.y = __builtin_amdgcn_exp2f(a.y);
    return r;
}

struct UniCoef {
    float A, B0, C0, B6, C6, bH, cH, kR, rho, rho2, LC, HC, sB, sC;
};

// Two pixels through the biased half-step chain + sigmoid. 8 hw-trans total.
__device__ __forceinline__ void chain2(v2f v, const UniCoef& u, v2f* acc2) {
    v2f vg = __builtin_elementwise_min(
                 __builtin_elementwise_max(v, (v2f){u.LC, u.LC}),
                 (v2f){u.HC, u.HC});
    v2f q  = vg * vg;
    v2f t0 = u.A * q + (u.B0 * vg + u.C0);      // biased log2 of bin0
    v2f t6 = u.A * q + (u.B6 * vg + u.C6);      // biased log2 of bin6
    v2f aH = u.bH * vg + (v2f){u.cH, u.cH};     // log2 of half-step ratio
    v2f g   = exp2v(t0);                        // 2 x v_exp
    v2f r05 = exp2v(aH);                        // 2 x v_exp
    v2f h   = exp2v(t6);                        // 2 x v_exp
    acc2[0] += g;
    g *= r05; acc2[1] += g;                     // bin1 = bin0 * r05
    v2f rr = r05 * r05 * (v2f){u.kR, u.kR};     // full-step ratio r_1
    g *= rr; acc2[2] += g; rr *= u.rho;
    g *= rr; acc2[3] += g; rr *= u.rho;
    g *= rr; acc2[4] += g; rr *= u.rho;
    g *= rr; acc2[5] += g; rr *= u.rho2;        // rr: r_4 -> r_6
    acc2[6] += h;
    h *= rr; acc2[7] += h; rr *= u.rho;
    h *= rr; acc2[8] += h; rr *= u.rho;
    h *= rr; acc2[9] += h;
    // sigmoid: s = sB*v + sC (UNclamped v); sigma = 1/(1+2^s)
    v2f s = u.sB * v + (v2f){u.sC, u.sC};
    v2f a; a.x = fabsf(s.x); a.y = fabsf(s.y);
    v2f tt = __builtin_elementwise_max(-a, (v2f){-200.0f, -200.0f});
    v2f uu = exp2v(tt);                         // 2 x v_exp; in (0,1]
    v2f xx = uu + (v2f){1.0f, 1.0f};            // in [1,2]
    v2f y  = (v2f){-0.47058824f, -0.47058824f} * xx
           + (v2f){1.41176471f, 1.41176471f};   // [1,2] minimax seed
    y = y * ((v2f){2.0f, 2.0f} - xx * y);
    y = y * ((v2f){2.0f, 2.0f} - xx * y);       // 1/(1+u), rel ~1.2e-5
    v2f qq = uu * y;                            // u/(1+u)
    v2f om = (v2f){1.0f, 1.0f} - qq;
    v2f sig;
    sig.x = (s.x > 0.0f) ? qq.x : om.x;
    sig.y = (s.y > 0.0f) ? qq.y : om.y;
    acc2[10] += sig;
}

__global__ __launch_bounds__(256)
void hist_kernel(const float* __restrict__ x,
                 const float* __restrict__ edges,
                 float* __restrict__ out) {
    const int bc  = blockIdx.x;          // bt*NCH + c
    const int c   = bc & (NCH - 1);
    const int tid = threadIdx.x;

    // Pixel loads FIRST (longest latency), edges after, setup overlaps.
    const float4* xp = (const float4*)(x + (size_t)bc * HW);
    const bool tail = tid < (HW4 - 768);
    float4 p0 = xp[tid];
    float4 p1 = xp[tid + 256];
    float4 p2 = xp[tid + 512];
    float4 p3 = xp[tail ? 768 + tid : tid];   // safe unconditional load

    const float LOG2E = 1.4426950408889634f;
    float e[NE];
    #pragma unroll
    for (int j = 0; j < NE; ++j) e[j] = rfl(edges[c * NE + j]);

    v2f acc2[NBINS];
    #pragma unroll
    for (int j = 0; j < NBINS; ++j) acc2[j] = (v2f){0.f, 0.f};

    const float D = e[1] - e[0];
    bool uniform = (D > 1e-6f);
    #pragma unroll
    for (int j = 1; j < NE - 1; ++j)
        uniform = uniform && (fabsf((e[j + 1] - e[j]) - D) <= 1e-4f * fabsf(D));

    const float sB = rfl(-20.0f * LOG2E);
    const float sC = rfl(20.0f * LOG2E * e[NE - 1]);

    if (uniform) {
        UniCoef u;
        const float sg  = -D * (1.0f / 3.0f) + 1e-6f;
        const float A   = rfl(-0.5f * LOG2E / (sg * sg));   // < 0 (log2 space)
        const float mu6 = e[0] + 5.5f * D;
        u.A  = A;
        u.B0 = rfl(-2.0f * A * e[0]); u.C0 = rfl(A * e[0] * e[0] + BIAS);
        u.B6 = rfl(-2.0f * A * mu6);  u.C6 = rfl(A * mu6 * mu6 + BIAS);
        u.bH = rfl(-A * D);                                   // dB/2 > 0
        u.cH = rfl(A * (0.5f * D) * (2.0f * e[0] + 0.5f * D));
        const float dC = rfl(A * D * (2.0f * e[0] + 2.0f * D));
        u.kR = rfl(__builtin_amdgcn_exp2f(1.5f * A * D * D)); // dC - 2cH
        u.rho  = rfl(__builtin_amdgcn_exp2f(2.0f * A * D * D));
        u.rho2 = rfl(u.rho * u.rho);
        // HC: full-step ratio <= 2^126 AND r05 <= 2^63 (so r05^2 finite).
        u.HC = rfl(fminf((126.0f - dC) / (2.0f * u.bH),
                         (63.0f - u.cH) / u.bH));
        // LC: anchor exactly at the normal-range boundary; below it every
        // bin's true value < 2^-126 unbiased-equivalent.
        u.LC = rfl(e[0] - __builtin_amdgcn_sqrtf((BIAS + 126.0f) / (-A)));
        u.sB = sB; u.sC = sC;

        chain2((v2f){p0.x, p0.y}, u, acc2);
        chain2((v2f){p0.z, p0.w}, u, acc2);
        __builtin_amdgcn_sched_barrier(0);
        chain2((v2f){p1.x, p1.y}, u, acc2);
        chain2((v2f){p1.z, p1.w}, u, acc2);
        __builtin_amdgcn_sched_barrier(0);
        chain2((v2f){p2.x, p2.y}, u, acc2);
        chain2((v2f){p2.z, p2.w}, u, acc2);
        __builtin_amdgcn_sched_barrier(0);
        {
            float s0 = tail ? p3.x : -1e18f;
            float s1 = tail ? p3.y : -1e18f;
            float s2 = tail ? p3.z : -1e18f;
            float s3 = tail ? p3.w : -1e18f;
            chain2((v2f){s0, s1}, u, acc2);
            chain2((v2f){s2, s3}, u, acc2);
        }
    } else {
        // General path: direct per-bin quadratic exp2 (rare; hw trans).
        float As[NE], Bs[NE], Cs[NE];
        {
            float mu = e[0];
            float s2 = (e[0] - e[1]) * (1.0f / 3.0f) + 1e-6f;
            float kk = -0.5f * LOG2E / (s2 * s2);
            As[0] = rfl(kk); Bs[0] = rfl(-2.0f * kk * mu); Cs[0] = rfl(kk * mu * mu);
        }
        #pragma unroll
        for (int j = 1; j < NE; ++j) {
            float mu = (e[j - 1] + e[j]) * 0.5f;
            float s2 = (e[j - 1] - e[j]) * (1.0f / 3.0f) + 1e-6f;
            float kk = -0.5f * LOG2E / (s2 * s2);
            As[j] = rfl(kk); Bs[j] = rfl(-2.0f * kk * mu); Cs[j] = rfl(kk * mu * mu);
        }
        float vsg[16] = {p0.x,p0.y,p0.z,p0.w, p1.x,p1.y,p1.z,p1.w,
                         p2.x,p2.y,p2.z,p2.w,
                         tail ? p3.x : -1e18f, tail ? p3.y : -1e18f,
                         tail ? p3.z : -1e18f, tail ? p3.w : -1e18f};
        #pragma unroll
        for (int k = 0; k < 16; ++k) {
            float v = vsg[k], v2 = v * v;
            #pragma unroll
            for (int j = 0; j < NE; ++j) {
                float arg = fmaf(As[j], v2, fmaf(Bs[j], v, Cs[j]));
                acc2[j].x += __builtin_amdgcn_exp2f(arg);
            }
            float den = 1.0f + __builtin_amdgcn_exp2f(fmaf(sB, v, sC));
            acc2[10].x += __builtin_amdgcn_rcpf(den);
        }
    }

    float acc[NBINS];
    #pragma unroll
    for (int j = 0; j < NBINS; ++j) acc[j] = acc2[j].x + acc2[j].y;

    // Wave (64-lane) reduce each accumulator.
    #pragma unroll
    for (int j = 0; j < NBINS; ++j) {
        float a = acc[j];
        #pragma unroll
        for (int off = 32; off > 0; off >>= 1)
            a += __shfl_down(a, off, 64);
        acc[j] = a;
    }

    // Cross-wave reduce via LDS (4 waves x 11 bins).
    __shared__ float red[4][NBINS];
    const int wave = tid >> 6;
    const int lane = tid & 63;
    if (lane == 0) {
        #pragma unroll
        for (int j = 0; j < NBINS; ++j) red[wave][j] = acc[j];
    }
    __syncthreads();
    if (tid < NBINS) {
        float s = red[0][tid] + red[1][tid] + red[2][tid] + red[3][tid];
        const float unb = (uniform && tid < NE) ? 0x1p-110f : 1.0f;
        out[(size_t)bc * NBINS + tid] = s * unb;
    }
}

extern "C" void kernel_launch(void* const* d_in, const int* in_sizes, int n_in,
                              void* d_out, int out_size, void* d_ws, size_t ws_size,
                              hipStream_t stream) {
    const float* x     = (const float*)d_in[0];
    const float* edges = (const float*)d_in[1];
    float* out         = (float*)d_out;
    hist_kernel<<<dim3(16 * NCH), dim3(256), 0, stream>>>(x, edges, out);
}

// Round 14
// 17.487 us; speedup vs baseline: 1.2727x; 1.0019x over previous
//
#include <hip/hip_runtime.h>

// HistByProfMultiChannel: x (16,128,56,56) f32, hist_edges (128,10) f32,
// out (16,128,11) f32.
//
// R14: half-step-ratio chain WITHOUT sched_barrier fences.
//  - R13's fences cost +67 cy/pair (371 vs R10's 304): the geometric chain
//    is a serial mul string; the scheduler needs freedom to interleave
//    chain2 calls across chunks for ILP. Fences removed; algebra kept.
//  - 8 trans/pair = algorithmic floor (2 FTZ anchors + 1 ratio + 1 sigmoid
//    exp2 per px): r05 = exp2(bH*v + cH) gives bin1 = bin0*r05 AND the
//    full-step ratio r_1 = r05^2 * kR.
//  - BIAS 110; acc[0..9] unbiased by 2^-110 at the end (exact).
//  - Sigmoid: hw exp2 + Newton reciprocal on [1,2] (seed 24/17 - 8/17*x).
//  - vg clamped to [LC,HC]: LC = anchor normal-range boundary (sentinel
//    safe), HC keeps r05^2 and the full ratio finite.

#define NE 10
#define NBINS 11
#define HW 3136
#define HW4 784
#define NCH 128
#define BIAS 110.0f

typedef float v2f __attribute__((ext_vector_type(2)));

__device__ __forceinline__ float rfl(float xv) {
    return __int_as_float(__builtin_amdgcn_readfirstlane(__float_as_int(xv)));
}
__device__ __forceinline__ v2f exp2v(v2f a) {
    v2f r;
    r.x = __builtin_amdgcn_exp2f(a.x);
    r.y = __builtin_amdgcn_exp2f(a.y);
    return r;
}

struct UniCoef {
    float A, B0, C0, B6, C6, bH, cH, kR, rho, rho2, LC, HC, sB, sC;
};

// Two pixels through the biased half-step chain + sigmoid. 8 hw-trans total.
__device__ __forceinline__ void chain2(v2f v, const UniCoef& u, v2f* acc2) {
    v2f vg = __builtin_elementwise_min(
                 __builtin_elementwise_max(v, (v2f){u.LC, u.LC}),
                 (v2f){u.HC, u.HC});
    v2f q  = vg * vg;
    v2f t0 = u.A * q + (u.B0 * vg + u.C0);      // biased log2 of bin0
    v2f t6 = u.A * q + (u.B6 * vg + u.C6);      // biased log2 of bin6
    v2f aH = u.bH * vg + (v2f){u.cH, u.cH};     // log2 of half-step ratio
    v2f g   = exp2v(t0);
    v2f r05 = exp2v(aH);
    v2f h   = exp2v(t6);
    acc2[0] += g;
    g *= r05; acc2[1] += g;                     // bin1 = bin0 * r05
    v2f rr = r05 * r05 * (v2f){u.kR, u.kR};     // full-step ratio r_1
    g *= rr; acc2[2] += g; rr *= u.rho;
    g *= rr; acc2[3] += g; rr *= u.rho;
    g *= rr; acc2[4] += g; rr *= u.rho;
    g *= rr; acc2[5] += g; rr *= u.rho2;        // rr: r_4 -> r_6
    acc2[6] += h;
    h *= rr; acc2[7] += h; rr *= u.rho;
    h *= rr; acc2[8] += h; rr *= u.rho;
    h *= rr; acc2[9] += h;
    // sigmoid: s = sB*v + sC (UNclamped v); sigma = 1/(1+2^s)
    v2f s = u.sB * v + (v2f){u.sC, u.sC};
    v2f a; a.x = fabsf(s.x); a.y = fabsf(s.y);
    v2f tt = __builtin_elementwise_max(-a, (v2f){-200.0f, -200.0f});
    v2f uu = exp2v(tt);                         // 2^{-|s|} in (0,1]
    v2f xx = uu + (v2f){1.0f, 1.0f};            // in [1,2]
    v2f y  = (v2f){-0.47058824f, -0.47058824f} * xx
           + (v2f){1.41176471f, 1.41176471f};   // [1,2] minimax seed
    y = y * ((v2f){2.0f, 2.0f} - xx * y);
    y = y * ((v2f){2.0f, 2.0f} - xx * y);       // 1/(1+u), rel ~1.2e-5
    v2f qq = uu * y;                            // u/(1+u)
    v2f om = (v2f){1.0f, 1.0f} - qq;
    v2f sig;
    sig.x = (s.x > 0.0f) ? qq.x : om.x;
    sig.y = (s.y > 0.0f) ? qq.y : om.y;
    acc2[10] += sig;
}

__global__ __launch_bounds__(256)
void hist_kernel(const float* __restrict__ x,
                 const float* __restrict__ edges,
                 float* __restrict__ out) {
    const int bc  = blockIdx.x;          // bt*NCH + c
    const int c   = bc & (NCH - 1);
    const int tid = threadIdx.x;

    // Pixel loads first (longest latency); coefficient setup overlaps.
    const float4* xp = (const float4*)(x + (size_t)bc * HW);
    const bool tail = tid < (HW4 - 768);
    float4 p0 = xp[tid];
    float4 p1 = xp[tid + 256];
    float4 p2 = xp[tid + 512];
    float4 p3 = xp[tail ? 768 + tid : tid];   // safe unconditional load

    const float LOG2E = 1.4426950408889634f;
    float e[NE];
    #pragma unroll
    for (int j = 0; j < NE; ++j) e[j] = rfl(edges[c * NE + j]);

    v2f acc2[NBINS];
    #pragma unroll
    for (int j = 0; j < NBINS; ++j) acc2[j] = (v2f){0.f, 0.f};

    const float D = e[1] - e[0];
    bool uniform = (D > 1e-6f);
    #pragma unroll
    for (int j = 1; j < NE - 1; ++j)
        uniform = uniform && (fabsf((e[j + 1] - e[j]) - D) <= 1e-4f * fabsf(D));

    const float sB = rfl(-20.0f * LOG2E);
    const float sC = rfl(20.0f * LOG2E * e[NE - 1]);

    if (uniform) {
        UniCoef u;
        const float sg  = -D * (1.0f / 3.0f) + 1e-6f;
        const float A   = rfl(-0.5f * LOG2E / (sg * sg));   // < 0 (log2 space)
        const float mu6 = e[0] + 5.5f * D;
        u.A  = A;
        u.B0 = rfl(-2.0f * A * e[0]); u.C0 = rfl(A * e[0] * e[0] + BIAS);
        u.B6 = rfl(-2.0f * A * mu6);  u.C6 = rfl(A * mu6 * mu6 + BIAS);
        u.bH = rfl(-A * D);                                   // dB/2 > 0
        u.cH = rfl(A * (0.5f * D) * (2.0f * e[0] + 0.5f * D));
        const float dC = rfl(A * D * (2.0f * e[0] + 2.0f * D));
        u.kR = rfl(__builtin_amdgcn_exp2f(1.5f * A * D * D));
        u.rho  = rfl(__builtin_amdgcn_exp2f(2.0f * A * D * D));
        u.rho2 = rfl(u.rho * u.rho);
        u.HC = rfl(fminf((126.0f - dC) / (2.0f * u.bH),
                         (63.0f - u.cH) / u.bH));
        u.LC = rfl(e[0] - __builtin_amdgcn_sqrtf((BIAS + 126.0f) / (-A)));
        u.sB = sB; u.sC = sC;

        const float t0x = tail ? p3.x : -1e18f;
        const float t1x = tail ? p3.y : -1e18f;
        const float t2x = tail ? p3.z : -1e18f;
        const float t3x = tail ? p3.w : -1e18f;

        chain2((v2f){p0.x, p0.y}, u, acc2);
        chain2((v2f){p0.z, p0.w}, u, acc2);
        chain2((v2f){p1.x, p1.y}, u, acc2);
        chain2((v2f){p1.z, p1.w}, u, acc2);
        chain2((v2f){p2.x, p2.y}, u, acc2);
        chain2((v2f){p2.z, p2.w}, u, acc2);
        chain2((v2f){t0x, t1x}, u, acc2);
        chain2((v2f){t2x, t3x}, u, acc2);
    } else {
        // General path: direct per-bin quadratic exp2 (rare; hw trans).
        float As[NE], Bs[NE], Cs[NE];
        {
            float mu = e[0];
            float s2 = (e[0] - e[1]) * (1.0f / 3.0f) + 1e-6f;
            float kk = -0.5f * LOG2E / (s2 * s2);
            As[0] = rfl(kk); Bs[0] = rfl(-2.0f * kk * mu); Cs[0] = rfl(kk * mu * mu);
        }
        #pragma unroll
        for (int j = 1; j < NE; ++j) {
            float mu = (e[j - 1] + e[j]) * 0.5f;
            float s2 = (e[j - 1] - e[j]) * (1.0f / 3.0f) + 1e-6f;
            float kk = -0.5f * LOG2E / (s2 * s2);
            As[j] = rfl(kk); Bs[j] = rfl(-2.0f * kk * mu); Cs[j] = rfl(kk * mu * mu);
        }
        float vsg[16] = {p0.x,p0.y,p0.z,p0.w, p1.x,p1.y,p1.z,p1.w,
                         p2.x,p2.y,p2.z,p2.w,
                         tail ? p3.x : -1e18f, tail ? p3.y : -1e18f,
                         tail ? p3.z : -1e18f, tail ? p3.w : -1e18f};
        #pragma unroll
        for (int k = 0; k < 16; ++k) {
            float v = vsg[k], v2 = v * v;
            #pragma unroll
            for (int j = 0; j < NE; ++j) {
                float arg = fmaf(As[j], v2, fmaf(Bs[j], v, Cs[j]));
                acc2[j].x += __builtin_amdgcn_exp2f(arg);
            }
            float den = 1.0f + __builtin_amdgcn_exp2f(fmaf(sB, v, sC));
            acc2[10].x += __builtin_amdgcn_rcpf(den);
        }
    }

    float acc[NBINS];
    #pragma unroll
    for (int j = 0; j < NBINS; ++j) acc[j] = acc2[j].x + acc2[j].y;

    // Wave (64-lane) reduce each accumulator.
    #pragma unroll
    for (int j = 0; j < NBINS; ++j) {
        float a = acc[j];
        #pragma unroll
        for (int off = 32; off > 0; off >>= 1)
            a += __shfl_down(a, off, 64);
        acc[j] = a;
    }

    // Cross-wave reduce via LDS (4 waves x 11 bins).
    __shared__ float red[4][NBINS];
    const int wave = tid >> 6;
    const int lane = tid & 63;
    if (lane == 0) {
        #pragma unroll
        for (int j = 0; j < NBINS; ++j) red[wave][j] = acc[j];
    }
    __syncthreads();
    if (tid < NBINS) {
        float s = red[0][tid] + red[1][tid] + red[2][tid] + red[3][tid];
        const float unb = (uniform && tid < NE) ? 0x1p-110f : 1.0f;
        out[(size_t)bc * NBINS + tid] = s * unb;
    }
}

extern "C" void kernel_launch(void* const* d_in, const int* in_sizes, int n_in,
                              void* d_out, int out_size, void* d_ws, size_t ws_size,
                              hipStream_t stream) {
    const float* x     = (const float*)d_in[0];
    const float* edges = (const float*)d_in[1];
    float* out         = (float*)d_out;
    hist_kernel<<<dim3(16 * NCH), dim3(256), 0, stream>>>(x, edges, out);
}

// Round 16
// 15.968 us; speedup vs baseline: 1.3938x; 1.0952x over previous
//
#include <hip/hip_runtime.h>

// HistByProfMultiChannel: x (16,128,56,56) f32, hist_edges (128,10) f32,
// out (16,128,11) f32.
//
// R16 = R10 restored verbatim (best known: 16.16us, absmax 0.5).
//  - Biased geometric chain: Gaussian terms carry a 2^88 bias so anchor FTZ
//    only occurs where the chained bin's true value <= 1.2e-6; acc[0..9]
//    unbiased by 2^-88 at the end (exact). Anchors at bins 0, 1, 6.
//    6 trans/px (exp2: t0, t1, t6, r, sigmoid; rcp).
//  - Chunk-local consumption: compute for chunk c touches only chunk c's
//    float4 registers -> compiler can wait vmcnt(3/2/1/0) progressively.
//  - Post-mortem R12-R15: the body is VALU-issue-bound (~86% VALUBusy at
//    probe). CDNA4 fp32 peak (157.3TF) equals the scalar SIMD-32 rate --
//    packed f32 buys no issue slots on this chip (unlike gfx90a), so the
//    ~300cy/pair body is a hard floor for this op count; trans-shaving
//    trades into the same VALU budget and loses. R10's mix is the optimum
//    found across 14 structural variants.

#define NE 10
#define NBINS 11
#define HW 3136
#define HW4 784
#define NCH 128
#define BIAS 88.0f

typedef float v2f __attribute__((ext_vector_type(2)));

__device__ __forceinline__ float rfl(float xv) {
    return __int_as_float(__builtin_amdgcn_readfirstlane(__float_as_int(xv)));
}
__device__ __forceinline__ v2f exp2v(v2f a) {
    v2f r;
    r.x = __builtin_amdgcn_exp2f(a.x);
    r.y = __builtin_amdgcn_exp2f(a.y);
    return r;
}

struct UniCoef {
    float A, B0, C0, B1, C1, B6, C6, dB, dC, rho, rho2, HC, sB, sC;
};

// Process two pixels (one v2f) through the biased chain.
__device__ __forceinline__ void chain2(v2f v, const UniCoef& u, v2f* acc2) {
    v2f vg = __builtin_elementwise_min(v, (v2f){u.HC, u.HC});
    v2f q  = vg * vg;
    v2f t0 = u.A * q + (u.B0 * vg + u.C0);
    v2f t1 = u.A * q + (u.B1 * vg + u.C1);
    v2f t6 = u.A * q + (u.B6 * vg + u.C6);
    v2f rr = exp2v(u.dB * vg + (v2f){u.dC, u.dC});
    acc2[0] += exp2v(t0);
    v2f g = exp2v(t1);
    acc2[1] += g;
    g *= rr; acc2[2] += g; rr *= u.rho;
    g *= rr; acc2[3] += g; rr *= u.rho;
    g *= rr; acc2[4] += g; rr *= u.rho;
    g *= rr; acc2[5] += g; rr *= u.rho2;   // rr: r4 -> r6
    v2f h = exp2v(t6);
    acc2[6] += h;
    h *= rr; acc2[7] += h; rr *= u.rho;
    h *= rr; acc2[8] += h; rr *= u.rho;
    h *= rr; acc2[9] += h;
    // sigmoid: s = sB*v + sC (UNclamped v); sigma = 1/(1+2^s)
    v2f sd = exp2v(u.sB * v + (v2f){u.sC, u.sC});
    v2f sig;
    sig.x = __builtin_amdgcn_rcpf(1.0f + sd.x);
    sig.y = __builtin_amdgcn_rcpf(1.0f + sd.y);
    acc2[10] += sig;
}

__global__ __launch_bounds__(256)
void hist_kernel(const float* __restrict__ x,
                 const float* __restrict__ edges,
                 float* __restrict__ out) {
    const int bc  = blockIdx.x;          // bt*NCH + c
    const int c   = bc & (NCH - 1);
    const int tid = threadIdx.x;

    const float LOG2E = 1.4426950408889634f;

    float e[NE];
    #pragma unroll
    for (int j = 0; j < NE; ++j) e[j] = rfl(edges[c * NE + j]);

    // Issue all 4 chunk loads up front; each chunk's compute consumes only
    // its own registers so the compiler waits vmcnt(3/2/1/0) progressively.
    const float4* xp = (const float4*)(x + (size_t)bc * HW);
    float4 p0 = xp[tid];
    float4 p1 = xp[tid + 256];
    float4 p2 = xp[tid + 512];
    float4 p3;
    if (tid < (HW4 - 768)) p3 = xp[768 + tid];
    else { p3.x = p3.y = p3.z = p3.w = -1e18f; }   // sentinel -> all profiles 0

    v2f acc2[NBINS];
    #pragma unroll
    for (int j = 0; j < NBINS; ++j) acc2[j] = (v2f){0.f, 0.f};

    const float D = e[1] - e[0];
    bool uniform = (D > 1e-6f);
    #pragma unroll
    for (int j = 1; j < NE - 1; ++j)
        uniform = uniform && (fabsf((e[j + 1] - e[j]) - D) <= 1e-4f * fabsf(D));

    const float sB = rfl(-20.0f * LOG2E);
    const float sC = rfl(20.0f * LOG2E * e[NE - 1]);

    if (uniform) {
        UniCoef u;
        const float sg  = -D * (1.0f / 3.0f) + 1e-6f;
        const float A   = rfl(-0.5f * LOG2E / (sg * sg));   // < 0 (log2 space)
        const float mu1 = e[0] + 0.5f * D;
        const float mu6 = e[0] + 5.5f * D;
        u.A  = A;
        u.B0 = rfl(-2.0f * A * e[0]); u.C0 = rfl(A * e[0] * e[0] + BIAS);
        u.B1 = rfl(-2.0f * A * mu1);  u.C1 = rfl(A * mu1 * mu1 + BIAS);
        u.B6 = rfl(-2.0f * A * mu6);  u.C6 = rfl(A * mu6 * mu6 + BIAS);
        u.dB = rfl(-2.0f * A * D);
        u.dC = rfl(A * D * (mu1 + mu1 + D));
        u.rho  = rfl(__builtin_amdgcn_exp2f(2.0f * A * D * D));   // < 1
        u.rho2 = rfl(u.rho * u.rho);
        u.HC = rfl((126.0f - u.dC) / u.dB);           // keep r finite
        u.sB = sB; u.sC = sC;

        // chunk 0 (waits only its own load)
        chain2((v2f){p0.x, p0.y}, u, acc2);
        chain2((v2f){p0.z, p0.w}, u, acc2);
        // chunk 1
        chain2((v2f){p1.x, p1.y}, u, acc2);
        chain2((v2f){p1.z, p1.w}, u, acc2);
        // chunk 2
        chain2((v2f){p2.x, p2.y}, u, acc2);
        chain2((v2f){p2.z, p2.w}, u, acc2);
        // chunk 3
        chain2((v2f){p3.x, p3.y}, u, acc2);
        chain2((v2f){p3.z, p3.w}, u, acc2);
    } else {
        // General path: direct per-bin quadratic exp2 (unbiased).
        float As[NE], Bs[NE], Cs[NE];
        {
            float mu = e[0];
            float s2 = (e[0] - e[1]) * (1.0f / 3.0f) + 1e-6f;
            float kk = -0.5f * LOG2E / (s2 * s2);
            As[0] = rfl(kk); Bs[0] = rfl(-2.0f * kk * mu); Cs[0] = rfl(kk * mu * mu);
        }
        #pragma unroll
        for (int j = 1; j < NE; ++j) {
            float mu = (e[j - 1] + e[j]) * 0.5f;
            float s2 = (e[j - 1] - e[j]) * (1.0f / 3.0f) + 1e-6f;
            float kk = -0.5f * LOG2E / (s2 * s2);
            As[j] = rfl(kk); Bs[j] = rfl(-2.0f * kk * mu); Cs[j] = rfl(kk * mu * mu);
        }
        float vsg[16] = {p0.x,p0.y,p0.z,p0.w, p1.x,p1.y,p1.z,p1.w,
                         p2.x,p2.y,p2.z,p2.w, p3.x,p3.y,p3.z,p3.w};
        #pragma unroll
        for (int k = 0; k < 16; ++k) {
            float v = vsg[k], v2 = v * v;
            #pragma unroll
            for (int j = 0; j < NE; ++j) {
                float arg = fmaf(As[j], v2, fmaf(Bs[j], v, Cs[j]));
                acc2[j].x += __builtin_amdgcn_exp2f(arg);
            }
            float den = 1.0f + __builtin_amdgcn_exp2f(fmaf(sB, v, sC));
            acc2[10].x += __builtin_amdgcn_rcpf(den);
        }
    }

    float acc[NBINS];
    #pragma unroll
    for (int j = 0; j < NBINS; ++j) acc[j] = acc2[j].x + acc2[j].y;

    // Wave (64-lane) reduce each accumulator.
    #pragma unroll
    for (int j = 0; j < NBINS; ++j) {
        float a = acc[j];
        #pragma unroll
        for (int off = 32; off > 0; off >>= 1)
            a += __shfl_down(a, off, 64);
        acc[j] = a;
    }

    // Cross-wave reduce via LDS (4 waves x 11 bins).
    __shared__ float red[4][NBINS];
    const int wave = tid >> 6;
    const int lane = tid & 63;
    if (lane == 0) {
        #pragma unroll
        for (int j = 0; j < NBINS; ++j) red[wave][j] = acc[j];
    }
    __syncthreads();
    if (tid < NBINS) {
        float s = red[0][tid] + red[1][tid] + red[2][tid] + red[3][tid];
        // Unbias Gaussian bins (uniform path only); sigmoid bin unbiased.
        const float unb = (uniform && tid < NE) ? 0x1p-88f : 1.0f;
        out[(size_t)bc * NBINS + tid] = s * unb;
    }
}

extern "C" void kernel_launch(void* const* d_in, const int* in_sizes, int n_in,
                              void* d_out, int out_size, void* d_ws, size_t ws_size,
                              hipStream_t stream) {
    const float* x     = (const float*)d_in[0];
    const float* edges = (const float*)d_in[1];
    float* out         = (float*)d_out;
    hist_kernel<<<dim3(16 * NCH), dim3(256), 0, stream>>>(x, edges, out);
}